// Round 6
// baseline (209.855 us; speedup 1.0000x reference)
//
#include <hip/hip_runtime.h>
#include <math.h>

#define KSEL 15
#define CIN 128
#define CF 16
#define HH 112
#define PLANE 12544      // 112*112
#define NN 256
#define ROWSTRIDE 20     // padded row-major feature row (18 used)
#define KVROW 272        // kv row stride in uints (bank-safe: 272=16*17)

static __device__ __forceinline__ unsigned mono32(float f) {
    unsigned u = __float_as_uint(f);
    return ((int)u < 0) ? ~u : (u | 0x80000000u);
}
static __device__ __forceinline__ float demono32(unsigned u) {
    return ((int)u < 0) ? __uint_as_float(u & 0x7FFFFFFFu) : __uint_as_float(~u);
}

// ---------------- K1: features (fp64 conv -> augment -> normalize) ----------------
__global__ __launch_bounds__(256) void k1_features(
    const float* __restrict__ x, const float* __restrict__ fw, const float* __restrict__ fb,
    double* __restrict__ xa64, float* __restrict__ xa32, float* __restrict__ xa32T,
    unsigned* __restrict__ dirtyCount)
{
    __shared__ float lfw[CIN * CF];   // [c][d]
    __shared__ float lfb[CF];
    const int tid = threadIdx.x;
    if (blockIdx.x == 0 && tid == 0) *dirtyCount = 0u;
    const int p  = blockIdx.x >> 2;
    const int n0 = (blockIdx.x & 3) * 64;
    const int b = p / 49, g = p % 49;
    const int gI = g / 7, gJ = g % 7;
    const float* xb = x + (size_t)b * CIN * PLANE + (size_t)(gI * 16 * HH + gJ * 16);

    for (int q = tid; q < CIN * CF; q += 256) { int d = q >> 7, c = q & 127; lfw[c * CF + d] = fw[q]; }
    if (tid < CF) lfb[tid] = fb[tid];
    __syncthreads();

    const int nl = tid >> 2, dq = tid & 3;
    const int n = n0 + nl, i = n >> 4, j = n & 15;
    const float* xp = xb + i * HH + j;

    // two accumulator sets (even/odd c) to halve the fp64 FMA dependency chain
    double e0 = 0.0, e1 = 0.0, e2 = 0.0, e3 = 0.0;
    double o0 = 0.0, o1 = 0.0, o2 = 0.0, o3 = 0.0;
#pragma unroll 2
    for (int c = 0; c < CIN; c += 2) {
        double xc0 = (double)xp[(size_t)c * PLANE];
        double xc1 = (double)xp[(size_t)(c + 1) * PLANE];
        float4 wv0 = *(const float4*)&lfw[c * CF + dq * 4];
        float4 wv1 = *(const float4*)&lfw[(c + 1) * CF + dq * 4];
        e0 = fma(xc0, (double)wv0.x, e0);
        e1 = fma(xc0, (double)wv0.y, e1);
        e2 = fma(xc0, (double)wv0.z, e2);
        e3 = fma(xc0, (double)wv0.w, e3);
        o0 = fma(xc1, (double)wv1.x, o0);
        o1 = fma(xc1, (double)wv1.y, o1);
        o2 = fma(xc1, (double)wv1.z, o2);
        o3 = fma(xc1, (double)wv1.w, o3);
    }
    double a0 = e0 + o0 + (double)lfb[dq * 4 + 0];
    double a1 = e1 + o1 + (double)lfb[dq * 4 + 1];
    double a2 = e2 + o2 + (double)lfb[dq * 4 + 2];
    double a3 = e3 + o3 + (double)lfb[dq * 4 + 3];

    const double GDIV = 4.618802153517006 + 1e-5;
    double gx = ((double)i - 7.5) / GDIV;
    double gy = ((double)j - 7.5) / GDIV;

    double ss = a0 * a0;
    ss = fma(a1, a1, ss); ss = fma(a2, a2, ss); ss = fma(a3, a3, ss);
    if (dq == 3) { ss = fma(gx, gx, ss); ss = fma(gy, gy, ss); }
    ss += __shfl_xor(ss, 1);
    ss += __shfl_xor(ss, 2);
    double nrm = fmax(sqrt(ss), 1e-8);

    size_t ro = ((size_t)p * NN + n) * ROWSTRIDE;
    double f0 = a0 / nrm, f1 = a1 / nrm, f2 = a2 / nrm, f3 = a3 / nrm;
    xa64[ro + dq * 4 + 0] = f0; xa64[ro + dq * 4 + 1] = f1;
    xa64[ro + dq * 4 + 2] = f2; xa64[ro + dq * 4 + 3] = f3;
    xa32[ro + dq * 4 + 0] = (float)f0; xa32[ro + dq * 4 + 1] = (float)f1;
    xa32[ro + dq * 4 + 2] = (float)f2; xa32[ro + dq * 4 + 3] = (float)f3;
    // transposed copy for K2's conflict-free B-side reads
    size_t tb = ((size_t)p * 18 + dq * 4) * NN + n;
    xa32T[tb + 0 * NN] = (float)f0;
    xa32T[tb + 1 * NN] = (float)f1;
    xa32T[tb + 2 * NN] = (float)f2;
    xa32T[tb + 3 * NN] = (float)f3;
    if (dq == 3) {
        double g0 = gx / nrm, g1 = gy / nrm;
        xa64[ro + 16] = g0; xa64[ro + 17] = g1; xa64[ro + 18] = 0.0; xa64[ro + 19] = 0.0;
        xa32[ro + 16] = (float)g0; xa32[ro + 17] = (float)g1; xa32[ro + 18] = 0.f; xa32[ro + 19] = 0.f;
        size_t tg = ((size_t)p * 18 + 16) * NN + n;
        xa32T[tg] = (float)g0; xa32T[tg + NN] = (float)g1;
    }
}

// ---------------- K2: transposed-tile sims -> conflict-free kv -> sort16+merge ----------------
__global__ __launch_bounds__(256) void k2_select(
    const float* __restrict__ xa32, const float* __restrict__ xa32T,
    const float* __restrict__ ea, const float* __restrict__ eb,
    int* __restrict__ topi, float* __restrict__ wkout,
    unsigned* __restrict__ dirtyCount, int* __restrict__ dirtyList)
{
    __shared__ float tileT[18 * NN];       // 18 KB, [d][m]
    __shared__ float rowTile[16 * ROWSTRIDE]; // 1.28 KB, block's 16 rows, row-major
    __shared__ unsigned kv[16 * KVROW];    // 17 KB, [row-in-block][m]
    const int tid = threadIdx.x;
    const int p = blockIdx.x >> 4, sub = blockIdx.x & 15;

    // stage transposed tile (coalesced global, consecutive-lane LDS writes: conflict-free)
    const float4* srcT = (const float4*)(xa32T + (size_t)p * 18 * NN);
    for (int q = tid; q < (18 * NN / 4); q += 256)
        ((float4*)tileT)[q] = srcT[q];
    // stage this block's 16 rows (row-major, for wave-uniform xr broadcasts)
    if (tid < (16 * ROWSTRIDE / 4)) {
        const float4* srcR = (const float4*)(xa32 + ((size_t)p * NN + sub * 16) * ROWSTRIDE);
        ((float4*)rowTile)[tid] = srcR[tid];
    }
    __syncthreads();

    // ---- phase 1: sims, 4 rows (per wave) x 4 m (per lane, consecutive) ----
    const int w    = tid >> 6;         // wave 0..3
    const int lane = tid & 63;
    const int m0   = lane * 4;

    float xr[4][18];
#pragma unroll
    for (int rr = 0; rr < 4; ++rr) {
        const float* rp_ = &rowTile[(w * 4 + rr) * ROWSTRIDE];
        float4 x0 = *(const float4*)&rp_[0];
        float4 x1 = *(const float4*)&rp_[4];
        float4 x2 = *(const float4*)&rp_[8];
        float4 x3 = *(const float4*)&rp_[12];
        float2 xt = *(const float2*)&rp_[16];
        xr[rr][0]=x0.x; xr[rr][1]=x0.y; xr[rr][2]=x0.z; xr[rr][3]=x0.w;
        xr[rr][4]=x1.x; xr[rr][5]=x1.y; xr[rr][6]=x1.z; xr[rr][7]=x1.w;
        xr[rr][8]=x2.x; xr[rr][9]=x2.y; xr[rr][10]=x2.z; xr[rr][11]=x2.w;
        xr[rr][12]=x3.x; xr[rr][13]=x3.y; xr[rr][14]=x3.z; xr[rr][15]=x3.w;
        xr[rr][16]=xt.x; xr[rr][17]=xt.y;
    }

    float s0[4], s1[4], s2[4], s3[4];   // sj[rr] = sim(row rr, m0+j)
#pragma unroll
    for (int rr = 0; rr < 4; ++rr) { s0[rr]=0.f; s1[rr]=0.f; s2[rr]=0.f; s3[rr]=0.f; }
#pragma unroll 6
    for (int d = 0; d < 18; ++d) {
        float4 bd = *(const float4*)&tileT[d * NN + m0];   // consecutive lanes: conflict-free
#pragma unroll
        for (int rr = 0; rr < 4; ++rr) {
            float a = xr[rr][d];
            s0[rr] = fmaf(a, bd.x, s0[rr]);
            s1[rr] = fmaf(a, bd.y, s1[rr]);
            s2[rr] = fmaf(a, bd.z, s2[rr]);
            s3[rr] = fmaf(a, bd.w, s3[rr]);
        }
    }
#pragma unroll
    for (int rr = 0; rr < 4; ++rr) {
        unsigned k0 = (mono32(s0[rr]) & 0xFFFFFF00u) | (unsigned)(255 - (m0 + 0));
        unsigned k1 = (mono32(s1[rr]) & 0xFFFFFF00u) | (unsigned)(255 - (m0 + 1));
        unsigned k2 = (mono32(s2[rr]) & 0xFFFFFF00u) | (unsigned)(255 - (m0 + 2));
        unsigned k3 = (mono32(s3[rr]) & 0xFFFFFF00u) | (unsigned)(255 - (m0 + 3));
        *(uint4*)&kv[(w * 4 + rr) * KVROW + m0] = make_uint4(k0, k1, k2, k3);  // conflict-free
    }
    __syncthreads();

    // ---- phase 2: per-row top-16 (16 lanes/row; lane owns m ≡ l16 mod 16) ----
    const int l16 = tid & 15;
    const int rb  = tid >> 4;
    const int row = p * NN + sub * 16 + rb;
    const int kvb = rb * KVROW + l16;

    unsigned k[16];
#pragma unroll
    for (int s = 0; s < 16; ++s) k[s] = kv[kvb + 16 * s];   // b32, ≤2-way: free

    // bitonic sort ascending (registers)
#pragma unroll
    for (int kk = 2; kk <= 16; kk <<= 1) {
#pragma unroll
        for (int jj = kk >> 1; jj > 0; jj >>= 1) {
#pragma unroll
            for (int ii = 0; ii < 16; ++ii) {
                int ll = ii ^ jj;
                if (ll > ii) {
                    bool up = ((ii & kk) == 0);
                    unsigned a = k[ii], bv = k[ll];
                    bool sw = up ? (a > bv) : (a < bv);
                    k[ii] = sw ? bv : a; k[ll] = sw ? a : bv;
                }
            }
        }
    }
    // write back sorted list (same-thread slots; only read by this thread's rare fallback)
#pragma unroll
    for (int s = 0; s < 16; ++s) kv[kvb + 16 * s] = k[s];

    // 16-round head merge; next-head from a 4-deep register window, LDS fallback (rare)
    unsigned h14 = k[14], h13 = k[13], h12 = k[12], h11 = k[11];
    int ptr = 15;
    unsigned myhead = k[15];
    unsigned mycand = 0;
#pragma unroll
    for (int e = 0; e < 16; ++e) {
        unsigned W = myhead, o;
        o = __shfl_xor(W, 1);  W = (o > W) ? o : W;
        o = __shfl_xor(W, 2);  W = (o > W) ? o : W;
        o = __shfl_xor(W, 4);  W = (o > W) ? o : W;
        o = __shfl_xor(W, 8);  W = (o > W) ? o : W;
        if (l16 == e) mycand = W;
        bool won = (myhead == W);
        if (won) {
            ptr--;
            int rp = ptr < 0 ? 0 : ptr;
            unsigned nh = h14;
            nh = (rp == 13) ? h13 : nh;
            nh = (rp == 12) ? h12 : nh;
            nh = (rp == 11) ? h11 : nh;
            if (rp <= 10) nh = kv[kvb + 16 * rp];   // divergent, rare
            myhead = nh;
        }
    }

    // certification: fp64 top-15 set == fp32 top-15 set unless boundary gap too small
    unsigned v15 = __shfl(mycand, 14, 16);
    unsigned v16 = __shfl(mycand, 15, 16);
    float lo = demono32(v15 & 0xFFFFFF00u) - 1e-5f;
    float hi = demono32((v16 & 0xFFFFFF00u) + 0x100u) + 1e-5f;
    bool dirty = !(hi < lo);
    if (l16 == 0 && dirty) {
        unsigned slot = atomicAdd(dirtyCount, 1u);
        dirtyList[slot] = row;
    }

    // weights from fp32 sims (clean rows; dirty rows overwritten by K2b)
    int mym = 255 - (int)(mycand & 0xFFu);
    float sv = demono32(mycand & 0xFFFFFF00u);
    float alpha = ea[0], beta = eb[0];
    float sg = 1.f / (1.f + expf(-(beta + alpha * sv)));
    float v = (l16 < KSEL) ? sg : -1e30f;
    float mx = v, of;
    of = __shfl_xor(mx, 1); mx = fmaxf(mx, of);
    of = __shfl_xor(mx, 2); mx = fmaxf(mx, of);
    of = __shfl_xor(mx, 4); mx = fmaxf(mx, of);
    of = __shfl_xor(mx, 8); mx = fmaxf(mx, of);
    float ex = expf(v - mx);
    float sm = ex;
    of = __shfl_xor(sm, 1); sm += of;
    of = __shfl_xor(sm, 2); sm += of;
    of = __shfl_xor(sm, 4); sm += of;
    of = __shfl_xor(sm, 8); sm += of;

    topi[row * 16 + l16] = mym;
    wkout[row * 16 + l16] = (l16 < KSEL) ? (ex / sm) : 0.f;
}

// ---------------- K2b: exact fp64 redo for dirty rows (persistent, wave per row) ----------------
__global__ __launch_bounds__(64) void k2b_dirty(
    const double* __restrict__ xa64, const float* __restrict__ ea, const float* __restrict__ eb,
    const unsigned* __restrict__ dirtyCount, const int* __restrict__ dirtyList,
    int* __restrict__ topi, float* __restrict__ wkout)
{
    const int nd = (int)*dirtyCount;
    const int lane = threadIdx.x;
    for (int idx = blockIdx.x; idx < nd; idx += gridDim.x) {
        const int row = dirtyList[idx];
        const int p = row >> 8;
        const double* xr64 = xa64 + (size_t)row * ROWSTRIDE;

        double sv[4]; int smi[4];
#pragma unroll
        for (int s4 = 0; s4 < 4; ++s4) {
            int m = s4 * 64 + lane;
            const double* xm64 = xa64 + ((size_t)p * NN + m) * ROWSTRIDE;
            double s = 0.0;
#pragma unroll
            for (int d = 0; d < 18; ++d) s = fma(xr64[d], xm64[d], s);
            sv[s4] = s; smi[s4] = m;
        }

        double cv = -3.0; int cm = 0;
#pragma unroll
        for (int e = 0; e < KSEL; ++e) {
            double lv = sv[0]; int lm = smi[0];
#pragma unroll
            for (int s4 = 1; s4 < 4; ++s4) {
                bool t = (sv[s4] > lv) || (sv[s4] == lv && smi[s4] < lm);
                lv = t ? sv[s4] : lv; lm = t ? smi[s4] : lm;
            }
#pragma unroll
            for (int off = 1; off < 64; off <<= 1) {
                double ov = __shfl_xor(lv, off);
                int    om = __shfl_xor(lm, off);
                bool t = (ov > lv) || (ov == lv && om < lm);
                lv = t ? ov : lv; lm = t ? om : lm;
            }
            if (lane == e) { cv = lv; cm = lm; }
#pragma unroll
            for (int s4 = 0; s4 < 4; ++s4) if (smi[s4] == lm) sv[s4] = -3.0;
        }

        float alpha = ea[0], beta = eb[0];
        float sg = 1.f / (1.f + expf(-(beta + alpha * (float)cv)));
        float v = (lane < KSEL) ? sg : -1e30f;
        float mx = v, of;
        for (int off = 1; off < 64; off <<= 1) { of = __shfl_xor(mx, off); mx = fmaxf(mx, of); }
        float ex = expf(v - mx);
        float sm = ex;
        for (int off = 1; off < 64; off <<= 1) { of = __shfl_xor(sm, off); sm += of; }
        float w = ex / sm;
        if (lane < 16) {
            topi[row * 16 + lane] = (lane < KSEL) ? cm : 0;
            wkout[row * 16 + lane] = (lane < KSEL) ? w : 0.f;
        }
    }
}

// ---------------- K3: weighted gather-aggregate ----------------
__global__ __launch_bounds__(256) void k3_aggregate(
    const float* __restrict__ x, const int* __restrict__ topi, const float* __restrict__ wk,
    float* __restrict__ out)
{
    __shared__ float tile[NN * ROWSTRIDE];   // [pos][20], 16 channels used
    const int tid = threadIdx.x;
    const int pb = blockIdx.x >> 3, cg = blockIdx.x & 7, c0 = cg * 16;
    const int b = pb / 49, g = pb % 49;
    const int gI = g / 7, gJ = g % 7;
    const float* xb = x + ((size_t)b * CIN + c0) * PLANE + (size_t)(gI * 16 * HH + gJ * 16);

#pragma unroll
    for (int rep = 0; rep < 4; ++rep) {
        int linear = rep * 256 + tid;
        int cc = linear >> 6, chunk = linear & 63;
        int pos = chunk * 4, ii = pos >> 4, jj = pos & 15;
        float4 v = *(const float4*)(xb + (size_t)cc * PLANE + ii * HH + jj);
        tile[(pos + 0) * ROWSTRIDE + cc] = v.x;
        tile[(pos + 1) * ROWSTRIDE + cc] = v.y;
        tile[(pos + 2) * ROWSTRIDE + cc] = v.z;
        tile[(pos + 3) * ROWSTRIDE + cc] = v.w;
    }
    __syncthreads();

    const int n = tid;
    const int row = pb * NN + n;
    float acc[16];
#pragma unroll
    for (int c = 0; c < 16; ++c) acc[c] = 0.f;

#pragma unroll
    for (int kq = 0; kq < 4; ++kq) {
        int4   mi4 = ((const int4*)(topi + (size_t)row * 16))[kq];
        float4 w4  = ((const float4*)(wk  + (size_t)row * 16))[kq];
        const int   mis[4] = { mi4.x, mi4.y, mi4.z, mi4.w };
        const float ws4[4] = { w4.x, w4.y, w4.z, w4.w };
#pragma unroll
        for (int u = 0; u < 4; ++u) {
            float w = ws4[u];
            const float4* sp = (const float4*)&tile[mis[u] * ROWSTRIDE];
#pragma unroll
            for (int q = 0; q < 4; ++q) {
                float4 f = sp[q];
                acc[q * 4 + 0] = fmaf(w, f.x, acc[q * 4 + 0]);
                acc[q * 4 + 1] = fmaf(w, f.y, acc[q * 4 + 1]);
                acc[q * 4 + 2] = fmaf(w, f.z, acc[q * 4 + 2]);
                acc[q * 4 + 3] = fmaf(w, f.w, acc[q * 4 + 3]);
            }
        }
    }
    const int ii = n >> 4, jj = n & 15;
    float* ob = out + ((size_t)b * CIN + c0) * PLANE + (size_t)(gI * 16 * HH + gJ * 16) + ii * HH + jj;
#pragma unroll
    for (int cc = 0; cc < 16; ++cc) ob[(size_t)cc * PLANE] = acc[cc];
}

extern "C" void kernel_launch(void* const* d_in, const int* in_sizes, int n_in,
                              void* d_out, int out_size, void* d_ws, size_t ws_size,
                              hipStream_t stream) {
    const float* x  = (const float*)d_in[0];
    const float* fw = (const float*)d_in[1];
    const float* fb = (const float*)d_in[2];
    const float* ea = (const float*)d_in[3];
    const float* eb = (const float*)d_in[4];
    float* out = (float*)d_out;

    int nB = in_sizes[0] / (CIN * PLANE);   // 4
    int nP = nB * 49;                       // 196
    size_t nRows = (size_t)nP * NN;         // 50176

    char* wsb = (char*)d_ws;
    size_t off = 0;
    auto carve = [&](size_t bytes) { char* r = wsb + off; off = (off + bytes + 255) & ~(size_t)255; return r; };
    double*   xa64   = (double*)  carve(nRows * ROWSTRIDE * sizeof(double));
    float*    xa32   = (float*)   carve(nRows * ROWSTRIDE * sizeof(float));
    float*    xa32T  = (float*)   carve((size_t)nP * 18 * NN * sizeof(float));
    int*      topi   = (int*)     carve(nRows * 16 * sizeof(int));
    float*    wk     = (float*)   carve(nRows * 16 * sizeof(float));
    unsigned* dcnt   = (unsigned*)carve(256);
    int*      dlist  = (int*)     carve(nRows * sizeof(int));

    hipLaunchKernelGGL(k1_features, dim3(nP * 4), dim3(256), 0, stream, x, fw, fb, xa64, xa32, xa32T, dcnt);
    hipLaunchKernelGGL(k2_select,   dim3(nP * 16), dim3(256), 0, stream, xa32, xa32T, ea, eb, topi, wk, dcnt, dlist);
    hipLaunchKernelGGL(k2b_dirty,   dim3(256), dim3(64), 0, stream, xa64, ea, eb, dcnt, dlist, topi, wk);
    hipLaunchKernelGGL(k3_aggregate, dim3(nP * 8), dim3(256), 0, stream, x, topi, wk, out);
}

// Round 7
// 158.398 us; speedup vs baseline: 1.3249x; 1.3249x over previous
//
#include <hip/hip_runtime.h>
#include <math.h>

#define KSEL 15
#define CIN 128
#define CF 16
#define HH 112
#define PLANE 12544      // 112*112
#define NN 256
#define ROWSTRIDE 20     // padded row-major feature row (18 used)
#define KVROW 272        // kv row stride in uints (bank-safe: 272=16*17)

static __device__ __forceinline__ unsigned mono32(float f) {
    unsigned u = __float_as_uint(f);
    return ((int)u < 0) ? ~u : (u | 0x80000000u);
}
static __device__ __forceinline__ float demono32(unsigned u) {
    return ((int)u < 0) ? __uint_as_float(u & 0x7FFFFFFFu) : __uint_as_float(~u);
}

// ---------------- K1: features (fp64 conv -> augment -> normalize) ----------------
__global__ __launch_bounds__(256) void k1_features(
    const float* __restrict__ x, const float* __restrict__ fw, const float* __restrict__ fb,
    double* __restrict__ xa64, float* __restrict__ xa32, float* __restrict__ xa32T,
    unsigned* __restrict__ dirtyCount)
{
    __shared__ float lfw[CIN * CF];   // [c][d]
    __shared__ float lfb[CF];
    const int tid = threadIdx.x;
    if (blockIdx.x == 0 && tid == 0) *dirtyCount = 0u;
    const int p  = blockIdx.x >> 2;
    const int n0 = (blockIdx.x & 3) * 64;
    const int b = p / 49, g = p % 49;
    const int gI = g / 7, gJ = g % 7;
    const float* xb = x + (size_t)b * CIN * PLANE + (size_t)(gI * 16 * HH + gJ * 16);

    for (int q = tid; q < CIN * CF; q += 256) { int d = q >> 7, c = q & 127; lfw[c * CF + d] = fw[q]; }
    if (tid < CF) lfb[tid] = fb[tid];
    __syncthreads();

    const int nl = tid >> 2, dq = tid & 3;
    const int n = n0 + nl, i = n >> 4, j = n & 15;
    const float* xp = xb + i * HH + j;

    // two accumulator sets (even/odd c) to halve the fp64 FMA dependency chain
    double e0 = 0.0, e1 = 0.0, e2 = 0.0, e3 = 0.0;
    double o0 = 0.0, o1 = 0.0, o2 = 0.0, o3 = 0.0;
#pragma unroll 2
    for (int c = 0; c < CIN; c += 2) {
        double xc0 = (double)xp[(size_t)c * PLANE];
        double xc1 = (double)xp[(size_t)(c + 1) * PLANE];
        float4 wv0 = *(const float4*)&lfw[c * CF + dq * 4];
        float4 wv1 = *(const float4*)&lfw[(c + 1) * CF + dq * 4];
        e0 = fma(xc0, (double)wv0.x, e0);
        e1 = fma(xc0, (double)wv0.y, e1);
        e2 = fma(xc0, (double)wv0.z, e2);
        e3 = fma(xc0, (double)wv0.w, e3);
        o0 = fma(xc1, (double)wv1.x, o0);
        o1 = fma(xc1, (double)wv1.y, o1);
        o2 = fma(xc1, (double)wv1.z, o2);
        o3 = fma(xc1, (double)wv1.w, o3);
    }
    double a0 = e0 + o0 + (double)lfb[dq * 4 + 0];
    double a1 = e1 + o1 + (double)lfb[dq * 4 + 1];
    double a2 = e2 + o2 + (double)lfb[dq * 4 + 2];
    double a3 = e3 + o3 + (double)lfb[dq * 4 + 3];

    const double GDIV = 4.618802153517006 + 1e-5;
    double gx = ((double)i - 7.5) / GDIV;
    double gy = ((double)j - 7.5) / GDIV;

    double ss = a0 * a0;
    ss = fma(a1, a1, ss); ss = fma(a2, a2, ss); ss = fma(a3, a3, ss);
    if (dq == 3) { ss = fma(gx, gx, ss); ss = fma(gy, gy, ss); }
    ss += __shfl_xor(ss, 1);
    ss += __shfl_xor(ss, 2);
    double nrm = fmax(sqrt(ss), 1e-8);

    size_t ro = ((size_t)p * NN + n) * ROWSTRIDE;
    double f0 = a0 / nrm, f1 = a1 / nrm, f2 = a2 / nrm, f3 = a3 / nrm;
    xa64[ro + dq * 4 + 0] = f0; xa64[ro + dq * 4 + 1] = f1;
    xa64[ro + dq * 4 + 2] = f2; xa64[ro + dq * 4 + 3] = f3;
    xa32[ro + dq * 4 + 0] = (float)f0; xa32[ro + dq * 4 + 1] = (float)f1;
    xa32[ro + dq * 4 + 2] = (float)f2; xa32[ro + dq * 4 + 3] = (float)f3;
    // transposed copy for K2's conflict-free B-side reads
    size_t tb = ((size_t)p * 18 + dq * 4) * NN + n;
    xa32T[tb + 0 * NN] = (float)f0;
    xa32T[tb + 1 * NN] = (float)f1;
    xa32T[tb + 2 * NN] = (float)f2;
    xa32T[tb + 3 * NN] = (float)f3;
    if (dq == 3) {
        double g0 = gx / nrm, g1 = gy / nrm;
        xa64[ro + 16] = g0; xa64[ro + 17] = g1; xa64[ro + 18] = 0.0; xa64[ro + 19] = 0.0;
        xa32[ro + 16] = (float)g0; xa32[ro + 17] = (float)g1; xa32[ro + 18] = 0.f; xa32[ro + 19] = 0.f;
        size_t tg = ((size_t)p * 18 + 16) * NN + n;
        xa32T[tg] = (float)g0; xa32T[tg + NN] = (float)g1;
    }
}

// ---------------- K2: transposed-tile sims -> conflict-free kv -> sort16+merge ----------------
__global__ __launch_bounds__(256) void k2_select(
    const float* __restrict__ xa32, const float* __restrict__ xa32T,
    const float* __restrict__ ea, const float* __restrict__ eb,
    int* __restrict__ topi, float* __restrict__ wkout,
    unsigned* __restrict__ dirtyCount, int* __restrict__ dirtyList)
{
    __shared__ float tileT[18 * NN];          // 18 KB, [d][m]
    __shared__ float rowTile[16 * ROWSTRIDE]; // 1.28 KB, block's 16 rows, row-major
    __shared__ unsigned kv[16 * KVROW];       // 17 KB, [row-in-block][m]
    const int tid = threadIdx.x;
    const int p = blockIdx.x >> 4, sub = blockIdx.x & 15;

    // stage transposed tile (coalesced global, consecutive-lane LDS writes: conflict-free)
    const float4* srcT = (const float4*)(xa32T + (size_t)p * 18 * NN);
    for (int q = tid; q < (18 * NN / 4); q += 256)
        ((float4*)tileT)[q] = srcT[q];
    // stage this block's 16 rows (row-major, for wave-uniform xr broadcasts)
    if (tid < (16 * ROWSTRIDE / 4)) {
        const float4* srcR = (const float4*)(xa32 + ((size_t)p * NN + sub * 16) * ROWSTRIDE);
        ((float4*)rowTile)[tid] = srcR[tid];
    }
    __syncthreads();

    // ---- phase 1: sims; wave owns 4 rows, two passes of 2 rows (VGPR-bounded, fully unrolled) ----
    const int w    = tid >> 6;         // wave 0..3
    const int lane = tid & 63;
    const int m0   = lane * 4;

#pragma unroll
    for (int half = 0; half < 2; ++half) {
        const int r0 = w * 4 + half * 2;   // row-in-block of first of the 2 rows
        float xr0[18], xr1[18];
        const float* rpA = &rowTile[(r0 + 0) * ROWSTRIDE];
        const float* rpB = &rowTile[(r0 + 1) * ROWSTRIDE];
#pragma unroll
        for (int d = 0; d < 18; ++d) { xr0[d] = rpA[d]; xr1[d] = rpB[d]; }  // wave-uniform broadcast

        float a0 = 0.f, a1 = 0.f, a2 = 0.f, a3 = 0.f;   // row r0,   m0..m0+3
        float b0 = 0.f, b1 = 0.f, b2 = 0.f, b3 = 0.f;   // row r0+1, m0..m0+3
#pragma unroll
        for (int d = 0; d < 18; ++d) {
            float4 bd = *(const float4*)&tileT[d * NN + m0];   // consecutive lanes: conflict-free
            float xA = xr0[d], xB = xr1[d];
            a0 = fmaf(xA, bd.x, a0); a1 = fmaf(xA, bd.y, a1);
            a2 = fmaf(xA, bd.z, a2); a3 = fmaf(xA, bd.w, a3);
            b0 = fmaf(xB, bd.x, b0); b1 = fmaf(xB, bd.y, b1);
            b2 = fmaf(xB, bd.z, b2); b3 = fmaf(xB, bd.w, b3);
        }
        unsigned kA0 = (mono32(a0) & 0xFFFFFF00u) | (unsigned)(255 - (m0 + 0));
        unsigned kA1 = (mono32(a1) & 0xFFFFFF00u) | (unsigned)(255 - (m0 + 1));
        unsigned kA2 = (mono32(a2) & 0xFFFFFF00u) | (unsigned)(255 - (m0 + 2));
        unsigned kA3 = (mono32(a3) & 0xFFFFFF00u) | (unsigned)(255 - (m0 + 3));
        unsigned kB0 = (mono32(b0) & 0xFFFFFF00u) | (unsigned)(255 - (m0 + 0));
        unsigned kB1 = (mono32(b1) & 0xFFFFFF00u) | (unsigned)(255 - (m0 + 1));
        unsigned kB2 = (mono32(b2) & 0xFFFFFF00u) | (unsigned)(255 - (m0 + 2));
        unsigned kB3 = (mono32(b3) & 0xFFFFFF00u) | (unsigned)(255 - (m0 + 3));
        *(uint4*)&kv[(r0 + 0) * KVROW + m0] = make_uint4(kA0, kA1, kA2, kA3);
        *(uint4*)&kv[(r0 + 1) * KVROW + m0] = make_uint4(kB0, kB1, kB2, kB3);
    }
    __syncthreads();

    // ---- phase 2: per-row top-16 (16 lanes/row; lane owns m ≡ l16 mod 16) ----
    const int l16 = tid & 15;
    const int rb  = tid >> 4;
    const int row = p * NN + sub * 16 + rb;
    const int kvb = rb * KVROW + l16;

    unsigned k[16];
#pragma unroll
    for (int s = 0; s < 16; ++s) k[s] = kv[kvb + 16 * s];   // b32, ≤2-way: free

    // bitonic sort ascending (registers)
#pragma unroll
    for (int kk = 2; kk <= 16; kk <<= 1) {
#pragma unroll
        for (int jj = kk >> 1; jj > 0; jj >>= 1) {
#pragma unroll
            for (int ii = 0; ii < 16; ++ii) {
                int ll = ii ^ jj;
                if (ll > ii) {
                    bool up = ((ii & kk) == 0);
                    unsigned a = k[ii], bv = k[ll];
                    bool sw = up ? (a > bv) : (a < bv);
                    k[ii] = sw ? bv : a; k[ll] = sw ? a : bv;
                }
            }
        }
    }
    // write back sorted list (same-thread slots; only read by this thread's rare fallback)
#pragma unroll
    for (int s = 0; s < 16; ++s) kv[kvb + 16 * s] = k[s];

    // 16-round head merge; next-head from a 4-deep register window, LDS fallback (rare)
    unsigned h14 = k[14], h13 = k[13], h12 = k[12], h11 = k[11];
    int ptr = 15;
    unsigned myhead = k[15];
    unsigned mycand = 0;
#pragma unroll
    for (int e = 0; e < 16; ++e) {
        unsigned W = myhead, o;
        o = __shfl_xor(W, 1);  W = (o > W) ? o : W;
        o = __shfl_xor(W, 2);  W = (o > W) ? o : W;
        o = __shfl_xor(W, 4);  W = (o > W) ? o : W;
        o = __shfl_xor(W, 8);  W = (o > W) ? o : W;
        if (l16 == e) mycand = W;
        bool won = (myhead == W);
        if (won) {
            ptr--;
            int rp = ptr < 0 ? 0 : ptr;
            unsigned nh = h14;
            nh = (rp == 13) ? h13 : nh;
            nh = (rp == 12) ? h12 : nh;
            nh = (rp == 11) ? h11 : nh;
            if (rp <= 10) nh = kv[kvb + 16 * rp];   // divergent, rare
            myhead = nh;
        }
    }

    // certification: fp64 top-15 set == fp32 top-15 set unless boundary gap too small
    unsigned v15 = __shfl(mycand, 14, 16);
    unsigned v16 = __shfl(mycand, 15, 16);
    float lo = demono32(v15 & 0xFFFFFF00u) - 1e-5f;
    float hi = demono32((v16 & 0xFFFFFF00u) + 0x100u) + 1e-5f;
    bool dirty = !(hi < lo);
    if (l16 == 0 && dirty) {
        unsigned slot = atomicAdd(dirtyCount, 1u);
        dirtyList[slot] = row;
    }

    // weights from fp32 sims (clean rows; dirty rows overwritten by K2b)
    int mym = 255 - (int)(mycand & 0xFFu);
    float sv = demono32(mycand & 0xFFFFFF00u);
    float alpha = ea[0], beta = eb[0];
    float sg = 1.f / (1.f + expf(-(beta + alpha * sv)));
    float v = (l16 < KSEL) ? sg : -1e30f;
    float mx = v, of;
    of = __shfl_xor(mx, 1); mx = fmaxf(mx, of);
    of = __shfl_xor(mx, 2); mx = fmaxf(mx, of);
    of = __shfl_xor(mx, 4); mx = fmaxf(mx, of);
    of = __shfl_xor(mx, 8); mx = fmaxf(mx, of);
    float ex = expf(v - mx);
    float sm = ex;
    of = __shfl_xor(sm, 1); sm += of;
    of = __shfl_xor(sm, 2); sm += of;
    of = __shfl_xor(sm, 4); sm += of;
    of = __shfl_xor(sm, 8); sm += of;

    topi[row * 16 + l16] = mym;
    wkout[row * 16 + l16] = (l16 < KSEL) ? (ex / sm) : 0.f;
}

// ---------------- K2b: exact fp64 redo for dirty rows (persistent, wave per row) ----------------
__global__ __launch_bounds__(64) void k2b_dirty(
    const double* __restrict__ xa64, const float* __restrict__ ea, const float* __restrict__ eb,
    const unsigned* __restrict__ dirtyCount, const int* __restrict__ dirtyList,
    int* __restrict__ topi, float* __restrict__ wkout)
{
    const int nd = (int)*dirtyCount;
    const int lane = threadIdx.x;
    for (int idx = blockIdx.x; idx < nd; idx += gridDim.x) {
        const int row = dirtyList[idx];
        const int p = row >> 8;
        const double* xr64 = xa64 + (size_t)row * ROWSTRIDE;

        double sv[4]; int smi[4];
#pragma unroll
        for (int s4 = 0; s4 < 4; ++s4) {
            int m = s4 * 64 + lane;
            const double* xm64 = xa64 + ((size_t)p * NN + m) * ROWSTRIDE;
            double s = 0.0;
#pragma unroll
            for (int d = 0; d < 18; ++d) s = fma(xr64[d], xm64[d], s);
            sv[s4] = s; smi[s4] = m;
        }

        double cv = -3.0; int cm = 0;
#pragma unroll
        for (int e = 0; e < KSEL; ++e) {
            double lv = sv[0]; int lm = smi[0];
#pragma unroll
            for (int s4 = 1; s4 < 4; ++s4) {
                bool t = (sv[s4] > lv) || (sv[s4] == lv && smi[s4] < lm);
                lv = t ? sv[s4] : lv; lm = t ? smi[s4] : lm;
            }
#pragma unroll
            for (int off = 1; off < 64; off <<= 1) {
                double ov = __shfl_xor(lv, off);
                int    om = __shfl_xor(lm, off);
                bool t = (ov > lv) || (ov == lv && om < lm);
                lv = t ? ov : lv; lm = t ? om : lm;
            }
            if (lane == e) { cv = lv; cm = lm; }
#pragma unroll
            for (int s4 = 0; s4 < 4; ++s4) if (smi[s4] == lm) sv[s4] = -3.0;
        }

        float alpha = ea[0], beta = eb[0];
        float sg = 1.f / (1.f + expf(-(beta + alpha * (float)cv)));
        float v = (lane < KSEL) ? sg : -1e30f;
        float mx = v, of;
        for (int off = 1; off < 64; off <<= 1) { of = __shfl_xor(mx, off); mx = fmaxf(mx, of); }
        float ex = expf(v - mx);
        float sm = ex;
        for (int off = 1; off < 64; off <<= 1) { of = __shfl_xor(sm, off); sm += of; }
        float w = ex / sm;
        if (lane < 16) {
            topi[row * 16 + lane] = (lane < KSEL) ? cm : 0;
            wkout[row * 16 + lane] = (lane < KSEL) ? w : 0.f;
        }
    }
}

// ---------------- K3: weighted gather-aggregate ----------------
__global__ __launch_bounds__(256) void k3_aggregate(
    const float* __restrict__ x, const int* __restrict__ topi, const float* __restrict__ wk,
    float* __restrict__ out)
{
    __shared__ float tile[NN * ROWSTRIDE];   // [pos][20], 16 channels used
    const int tid = threadIdx.x;
    const int pb = blockIdx.x >> 3, cg = blockIdx.x & 7, c0 = cg * 16;
    const int b = pb / 49, g = pb % 49;
    const int gI = g / 7, gJ = g % 7;
    const float* xb = x + ((size_t)b * CIN + c0) * PLANE + (size_t)(gI * 16 * HH + gJ * 16);

#pragma unroll
    for (int rep = 0; rep < 4; ++rep) {
        int linear = rep * 256 + tid;
        int cc = linear >> 6, chunk = linear & 63;
        int pos = chunk * 4, ii = pos >> 4, jj = pos & 15;
        float4 v = *(const float4*)(xb + (size_t)cc * PLANE + ii * HH + jj);
        tile[(pos + 0) * ROWSTRIDE + cc] = v.x;
        tile[(pos + 1) * ROWSTRIDE + cc] = v.y;
        tile[(pos + 2) * ROWSTRIDE + cc] = v.z;
        tile[(pos + 3) * ROWSTRIDE + cc] = v.w;
    }
    __syncthreads();

    const int n = tid;
    const int row = pb * NN + n;
    float acc[16];
#pragma unroll
    for (int c = 0; c < 16; ++c) acc[c] = 0.f;

#pragma unroll
    for (int kq = 0; kq < 4; ++kq) {
        int4   mi4 = ((const int4*)(topi + (size_t)row * 16))[kq];
        float4 w4  = ((const float4*)(wk  + (size_t)row * 16))[kq];
        const int   mis[4] = { mi4.x, mi4.y, mi4.z, mi4.w };
        const float ws4[4] = { w4.x, w4.y, w4.z, w4.w };
#pragma unroll
        for (int u = 0; u < 4; ++u) {
            float w = ws4[u];
            const float4* sp = (const float4*)&tile[mis[u] * ROWSTRIDE];
#pragma unroll
            for (int q = 0; q < 4; ++q) {
                float4 f = sp[q];
                acc[q * 4 + 0] = fmaf(w, f.x, acc[q * 4 + 0]);
                acc[q * 4 + 1] = fmaf(w, f.y, acc[q * 4 + 1]);
                acc[q * 4 + 2] = fmaf(w, f.z, acc[q * 4 + 2]);
                acc[q * 4 + 3] = fmaf(w, f.w, acc[q * 4 + 3]);
            }
        }
    }
    const int ii = n >> 4, jj = n & 15;
    float* ob = out + ((size_t)b * CIN + c0) * PLANE + (size_t)(gI * 16 * HH + gJ * 16) + ii * HH + jj;
#pragma unroll
    for (int cc = 0; cc < 16; ++cc) ob[(size_t)cc * PLANE] = acc[cc];
}

extern "C" void kernel_launch(void* const* d_in, const int* in_sizes, int n_in,
                              void* d_out, int out_size, void* d_ws, size_t ws_size,
                              hipStream_t stream) {
    const float* x  = (const float*)d_in[0];
    const float* fw = (const float*)d_in[1];
    const float* fb = (const float*)d_in[2];
    const float* ea = (const float*)d_in[3];
    const float* eb = (const float*)d_in[4];
    float* out = (float*)d_out;

    int nB = in_sizes[0] / (CIN * PLANE);   // 4
    int nP = nB * 49;                       // 196
    size_t nRows = (size_t)nP * NN;         // 50176

    char* wsb = (char*)d_ws;
    size_t off = 0;
    auto carve = [&](size_t bytes) { char* r = wsb + off; off = (off + bytes + 255) & ~(size_t)255; return r; };
    double*   xa64   = (double*)  carve(nRows * ROWSTRIDE * sizeof(double));
    float*    xa32   = (float*)   carve(nRows * ROWSTRIDE * sizeof(float));
    float*    xa32T  = (float*)   carve((size_t)nP * 18 * NN * sizeof(float));
    int*      topi   = (int*)     carve(nRows * 16 * sizeof(int));
    float*    wk     = (float*)   carve(nRows * 16 * sizeof(float));
    unsigned* dcnt   = (unsigned*)carve(256);
    int*      dlist  = (int*)     carve(nRows * sizeof(int));

    hipLaunchKernelGGL(k1_features, dim3(nP * 4), dim3(256), 0, stream, x, fw, fb, xa64, xa32, xa32T, dcnt);
    hipLaunchKernelGGL(k2_select,   dim3(nP * 16), dim3(256), 0, stream, xa32, xa32T, ea, eb, topi, wk, dcnt, dlist);
    hipLaunchKernelGGL(k2b_dirty,   dim3(256), dim3(64), 0, stream, xa64, ea, eb, dcnt, dlist, topi, wk);
    hipLaunchKernelGGL(k3_aggregate, dim3(nP * 8), dim3(256), 0, stream, x, topi, wk, out);
}

// Round 8
// 153.889 us; speedup vs baseline: 1.3637x; 1.0293x over previous
//
#include <hip/hip_runtime.h>
#include <math.h>

#define KSEL 15
#define CIN 128
#define CF 16
#define HH 112
#define PLANE 12544      // 112*112
#define NN 256
#define ROWSTRIDE 20     // padded row-major feature row (18 used)
#define KVROW 260        // kv row stride in uints (reads lane-consecutive; 1040B rows, 16B-aligned)

static __device__ __forceinline__ unsigned mono32(float f) {
    unsigned u = __float_as_uint(f);
    return ((int)u < 0) ? ~u : (u | 0x80000000u);
}
static __device__ __forceinline__ float demono32(unsigned u) {
    return ((int)u < 0) ? __uint_as_float(u & 0x7FFFFFFFu) : __uint_as_float(~u);
}

// ---------------- K1: features (fp64 conv -> augment -> normalize) ----------------
__global__ __launch_bounds__(256) void k1_features(
    const float* __restrict__ x, const float* __restrict__ fw, const float* __restrict__ fb,
    double* __restrict__ xa64, float* __restrict__ xa32, float* __restrict__ xa32T,
    unsigned* __restrict__ dirtyCount)
{
    __shared__ float lfw[CIN * CF];   // [c][d]
    __shared__ float lfb[CF];
    const int tid = threadIdx.x;
    if (blockIdx.x == 0 && tid == 0) *dirtyCount = 0u;
    const int p  = blockIdx.x >> 2;
    const int n0 = (blockIdx.x & 3) * 64;
    const int b = p / 49, g = p % 49;
    const int gI = g / 7, gJ = g % 7;
    const float* xb = x + (size_t)b * CIN * PLANE + (size_t)(gI * 16 * HH + gJ * 16);

    for (int q = tid; q < CIN * CF; q += 256) { int d = q >> 7, c = q & 127; lfw[c * CF + d] = fw[q]; }
    if (tid < CF) lfb[tid] = fb[tid];
    __syncthreads();

    const int nl = tid >> 2, dq = tid & 3;
    const int n = n0 + nl, i = n >> 4, j = n & 15;
    const float* xp = xb + i * HH + j;

    // two accumulator sets (even/odd c) to halve the fp64 FMA dependency chain
    double e0 = 0.0, e1 = 0.0, e2 = 0.0, e3 = 0.0;
    double o0 = 0.0, o1 = 0.0, o2 = 0.0, o3 = 0.0;
#pragma unroll 2
    for (int c = 0; c < CIN; c += 2) {
        double xc0 = (double)xp[(size_t)c * PLANE];
        double xc1 = (double)xp[(size_t)(c + 1) * PLANE];
        float4 wv0 = *(const float4*)&lfw[c * CF + dq * 4];
        float4 wv1 = *(const float4*)&lfw[(c + 1) * CF + dq * 4];
        e0 = fma(xc0, (double)wv0.x, e0);
        e1 = fma(xc0, (double)wv0.y, e1);
        e2 = fma(xc0, (double)wv0.z, e2);
        e3 = fma(xc0, (double)wv0.w, e3);
        o0 = fma(xc1, (double)wv1.x, o0);
        o1 = fma(xc1, (double)wv1.y, o1);
        o2 = fma(xc1, (double)wv1.z, o2);
        o3 = fma(xc1, (double)wv1.w, o3);
    }
    double a0 = e0 + o0 + (double)lfb[dq * 4 + 0];
    double a1 = e1 + o1 + (double)lfb[dq * 4 + 1];
    double a2 = e2 + o2 + (double)lfb[dq * 4 + 2];
    double a3 = e3 + o3 + (double)lfb[dq * 4 + 3];

    const double GDIV = 4.618802153517006 + 1e-5;
    double gx = ((double)i - 7.5) / GDIV;
    double gy = ((double)j - 7.5) / GDIV;

    double ss = a0 * a0;
    ss = fma(a1, a1, ss); ss = fma(a2, a2, ss); ss = fma(a3, a3, ss);
    if (dq == 3) { ss = fma(gx, gx, ss); ss = fma(gy, gy, ss); }
    ss += __shfl_xor(ss, 1);
    ss += __shfl_xor(ss, 2);
    double nrm = fmax(sqrt(ss), 1e-8);

    size_t ro = ((size_t)p * NN + n) * ROWSTRIDE;
    double f0 = a0 / nrm, f1 = a1 / nrm, f2 = a2 / nrm, f3 = a3 / nrm;
    xa64[ro + dq * 4 + 0] = f0; xa64[ro + dq * 4 + 1] = f1;
    xa64[ro + dq * 4 + 2] = f2; xa64[ro + dq * 4 + 3] = f3;
    xa32[ro + dq * 4 + 0] = (float)f0; xa32[ro + dq * 4 + 1] = (float)f1;
    xa32[ro + dq * 4 + 2] = (float)f2; xa32[ro + dq * 4 + 3] = (float)f3;
    // transposed copy for K2's conflict-free B-side reads
    size_t tb = ((size_t)p * 18 + dq * 4) * NN + n;
    xa32T[tb + 0 * NN] = (float)f0;
    xa32T[tb + 1 * NN] = (float)f1;
    xa32T[tb + 2 * NN] = (float)f2;
    xa32T[tb + 3 * NN] = (float)f3;
    if (dq == 3) {
        double g0 = gx / nrm, g1 = gy / nrm;
        xa64[ro + 16] = g0; xa64[ro + 17] = g1; xa64[ro + 18] = 0.0; xa64[ro + 19] = 0.0;
        xa32[ro + 16] = (float)g0; xa32[ro + 17] = (float)g1; xa32[ro + 18] = 0.f; xa32[ro + 19] = 0.f;
        size_t tg = ((size_t)p * 18 + 16) * NN + n;
        xa32T[tg] = (float)g0; xa32T[tg + NN] = (float)g1;
    }
}

// ---------------- K2: sims -> (kv aliased into tileT) -> sort16+merge ----------------
// LDS budget 19.8 KB -> 8 blocks/CU; launch_bounds(256,8) targets <=64 VGPR -> 32 waves/CU.
__global__ __launch_bounds__(256, 8) void k2_select(
    const float* __restrict__ xa32, const float* __restrict__ xa32T,
    const float* __restrict__ ea, const float* __restrict__ eb,
    int* __restrict__ topi, float* __restrict__ wkout,
    unsigned* __restrict__ dirtyCount, int* __restrict__ dirtyList)
{
    __shared__ float tileT[18 * NN];          // 18 KB, [d][m]; REUSED as kv after phase 1
    __shared__ float rowTile[16 * ROWSTRIDE]; // 1.3 KB, block's 16 rows, row-major
    unsigned* kv = (unsigned*)tileT;          // kv[16][KVROW], 16.6 KB <= 18 KB
    const int tid = threadIdx.x;
    const int p = blockIdx.x >> 4, sub = blockIdx.x & 15;

    // stage transposed tile (coalesced global, consecutive-lane LDS writes: conflict-free)
    const float4* srcT = (const float4*)(xa32T + (size_t)p * 18 * NN);
    for (int q = tid; q < (18 * NN / 4); q += 256)
        ((float4*)tileT)[q] = srcT[q];
    // stage this block's 16 rows (row-major, for b128 broadcast xr reads)
    if (tid < (16 * ROWSTRIDE / 4)) {
        const float4* srcR = (const float4*)(xa32 + ((size_t)p * NN + sub * 16) * ROWSTRIDE);
        ((float4*)rowTile)[tid] = srcR[tid];
    }
    __syncthreads();

    // ---- phase 1: sims; wave owns 4 rows, two passes of 2 rows; keys stay in registers ----
    const int w    = tid >> 6;         // wave 0..3
    const int lane = tid & 63;
    const int m0   = lane * 4;

    unsigned keys[16];                 // [half*8 + rowpair*4 + j]
#pragma unroll
    for (int half = 0; half < 2; ++half) {
        const int r0 = w * 4 + half * 2;
        float xr0[18], xr1[18];
        {
            const float* rpA = &rowTile[(r0 + 0) * ROWSTRIDE];
            const float* rpB = &rowTile[(r0 + 1) * ROWSTRIDE];
            float4 t0, t1, t2, t3; float2 tt;
            t0 = *(const float4*)&rpA[0];  t1 = *(const float4*)&rpA[4];
            t2 = *(const float4*)&rpA[8];  t3 = *(const float4*)&rpA[12];
            tt = *(const float2*)&rpA[16];
            xr0[0]=t0.x; xr0[1]=t0.y; xr0[2]=t0.z; xr0[3]=t0.w;
            xr0[4]=t1.x; xr0[5]=t1.y; xr0[6]=t1.z; xr0[7]=t1.w;
            xr0[8]=t2.x; xr0[9]=t2.y; xr0[10]=t2.z; xr0[11]=t2.w;
            xr0[12]=t3.x; xr0[13]=t3.y; xr0[14]=t3.z; xr0[15]=t3.w;
            xr0[16]=tt.x; xr0[17]=tt.y;
            t0 = *(const float4*)&rpB[0];  t1 = *(const float4*)&rpB[4];
            t2 = *(const float4*)&rpB[8];  t3 = *(const float4*)&rpB[12];
            tt = *(const float2*)&rpB[16];
            xr1[0]=t0.x; xr1[1]=t0.y; xr1[2]=t0.z; xr1[3]=t0.w;
            xr1[4]=t1.x; xr1[5]=t1.y; xr1[6]=t1.z; xr1[7]=t1.w;
            xr1[8]=t2.x; xr1[9]=t2.y; xr1[10]=t2.z; xr1[11]=t2.w;
            xr1[12]=t3.x; xr1[13]=t3.y; xr1[14]=t3.z; xr1[15]=t3.w;
            xr1[16]=tt.x; xr1[17]=tt.y;
        }

        float a0 = 0.f, a1 = 0.f, a2 = 0.f, a3 = 0.f;   // row r0
        float b0 = 0.f, b1 = 0.f, b2 = 0.f, b3 = 0.f;   // row r0+1
#pragma unroll
        for (int d = 0; d < 18; ++d) {
            float4 bd = *(const float4*)&tileT[d * NN + m0];   // consecutive lanes: conflict-free
            float xA = xr0[d], xB = xr1[d];
            a0 = fmaf(xA, bd.x, a0); a1 = fmaf(xA, bd.y, a1);
            a2 = fmaf(xA, bd.z, a2); a3 = fmaf(xA, bd.w, a3);
            b0 = fmaf(xB, bd.x, b0); b1 = fmaf(xB, bd.y, b1);
            b2 = fmaf(xB, bd.z, b2); b3 = fmaf(xB, bd.w, b3);
        }
        keys[half * 8 + 0] = (mono32(a0) & 0xFFFFFF00u) | (unsigned)(255 - (m0 + 0));
        keys[half * 8 + 1] = (mono32(a1) & 0xFFFFFF00u) | (unsigned)(255 - (m0 + 1));
        keys[half * 8 + 2] = (mono32(a2) & 0xFFFFFF00u) | (unsigned)(255 - (m0 + 2));
        keys[half * 8 + 3] = (mono32(a3) & 0xFFFFFF00u) | (unsigned)(255 - (m0 + 3));
        keys[half * 8 + 4] = (mono32(b0) & 0xFFFFFF00u) | (unsigned)(255 - (m0 + 0));
        keys[half * 8 + 5] = (mono32(b1) & 0xFFFFFF00u) | (unsigned)(255 - (m0 + 1));
        keys[half * 8 + 6] = (mono32(b2) & 0xFFFFFF00u) | (unsigned)(255 - (m0 + 2));
        keys[half * 8 + 7] = (mono32(b3) & 0xFFFFFF00u) | (unsigned)(255 - (m0 + 3));
    }
    __syncthreads();   // ALL waves' tileT reads complete before kv overwrites it

#pragma unroll
    for (int half = 0; half < 2; ++half) {
        const int r0 = w * 4 + half * 2;
        *(uint4*)&kv[(r0 + 0) * KVROW + m0] =
            make_uint4(keys[half*8+0], keys[half*8+1], keys[half*8+2], keys[half*8+3]);
        *(uint4*)&kv[(r0 + 1) * KVROW + m0] =
            make_uint4(keys[half*8+4], keys[half*8+5], keys[half*8+6], keys[half*8+7]);
    }
    __syncthreads();

    // ---- phase 2: per-row top-16 (16 lanes/row; lane owns m ≡ l16 mod 16) ----
    const int l16 = tid & 15;
    const int rb  = tid >> 4;
    const int row = p * NN + sub * 16 + rb;
    const int kvb = rb * KVROW + l16;

    unsigned k[16];
#pragma unroll
    for (int s = 0; s < 16; ++s) k[s] = kv[kvb + 16 * s];   // b32, lanes consecutive: free

    // bitonic sort ascending (registers)
#pragma unroll
    for (int kk = 2; kk <= 16; kk <<= 1) {
#pragma unroll
        for (int jj = kk >> 1; jj > 0; jj >>= 1) {
#pragma unroll
            for (int ii = 0; ii < 16; ++ii) {
                int ll = ii ^ jj;
                if (ll > ii) {
                    bool up = ((ii & kk) == 0);
                    unsigned a = k[ii], bv = k[ll];
                    bool sw = up ? (a > bv) : (a < bv);
                    k[ii] = sw ? bv : a; k[ll] = sw ? a : bv;
                }
            }
        }
    }
    // write back sorted list (same-thread slots; only read by this thread's rare fallback)
#pragma unroll
    for (int s = 0; s < 16; ++s) kv[kvb + 16 * s] = k[s];

    // 16-round head merge; next-head from a 4-deep register window, LDS fallback (rare)
    unsigned h14 = k[14], h13 = k[13], h12 = k[12], h11 = k[11];
    int ptr = 15;
    unsigned myhead = k[15];
    unsigned mycand = 0;
#pragma unroll
    for (int e = 0; e < 16; ++e) {
        unsigned W = myhead, o;
        o = __shfl_xor(W, 1);  W = (o > W) ? o : W;
        o = __shfl_xor(W, 2);  W = (o > W) ? o : W;
        o = __shfl_xor(W, 4);  W = (o > W) ? o : W;
        o = __shfl_xor(W, 8);  W = (o > W) ? o : W;
        if (l16 == e) mycand = W;
        bool won = (myhead == W);
        if (won) {
            ptr--;
            int rp = ptr < 0 ? 0 : ptr;
            unsigned nh = h14;
            nh = (rp == 13) ? h13 : nh;
            nh = (rp == 12) ? h12 : nh;
            nh = (rp == 11) ? h11 : nh;
            if (rp <= 10) nh = kv[kvb + 16 * rp];   // divergent, rare
            myhead = nh;
        }
    }

    // certification: fp64 top-15 set == fp32 top-15 set unless boundary gap too small
    unsigned v15 = __shfl(mycand, 14, 16);
    unsigned v16 = __shfl(mycand, 15, 16);
    float lo = demono32(v15 & 0xFFFFFF00u) - 1e-5f;
    float hi = demono32((v16 & 0xFFFFFF00u) + 0x100u) + 1e-5f;
    bool dirty = !(hi < lo);
    if (l16 == 0 && dirty) {
        unsigned slot = atomicAdd(dirtyCount, 1u);
        dirtyList[slot] = row;
    }

    // weights from fp32 sims (clean rows; dirty rows overwritten by K2b)
    int mym = 255 - (int)(mycand & 0xFFu);
    float sv = demono32(mycand & 0xFFFFFF00u);
    float alpha = ea[0], beta = eb[0];
    float sg = 1.f / (1.f + expf(-(beta + alpha * sv)));
    float v = (l16 < KSEL) ? sg : -1e30f;
    float mx = v, of;
    of = __shfl_xor(mx, 1); mx = fmaxf(mx, of);
    of = __shfl_xor(mx, 2); mx = fmaxf(mx, of);
    of = __shfl_xor(mx, 4); mx = fmaxf(mx, of);
    of = __shfl_xor(mx, 8); mx = fmaxf(mx, of);
    float ex = expf(v - mx);
    float sm = ex;
    of = __shfl_xor(sm, 1); sm += of;
    of = __shfl_xor(sm, 2); sm += of;
    of = __shfl_xor(sm, 4); sm += of;
    of = __shfl_xor(sm, 8); sm += of;

    topi[row * 16 + l16] = mym;
    wkout[row * 16 + l16] = (l16 < KSEL) ? (ex / sm) : 0.f;
}

// ---------------- K2b: exact fp64 redo for dirty rows (persistent, wave per row) ----------------
__global__ __launch_bounds__(64) void k2b_dirty(
    const double* __restrict__ xa64, const float* __restrict__ ea, const float* __restrict__ eb,
    const unsigned* __restrict__ dirtyCount, const int* __restrict__ dirtyList,
    int* __restrict__ topi, float* __restrict__ wkout)
{
    const int nd = (int)*dirtyCount;
    const int lane = threadIdx.x;
    for (int idx = blockIdx.x; idx < nd; idx += gridDim.x) {
        const int row = dirtyList[idx];
        const int p = row >> 8;
        const double* xr64 = xa64 + (size_t)row * ROWSTRIDE;

        double sv[4]; int smi[4];
#pragma unroll
        for (int s4 = 0; s4 < 4; ++s4) {
            int m = s4 * 64 + lane;
            const double* xm64 = xa64 + ((size_t)p * NN + m) * ROWSTRIDE;
            double s = 0.0;
#pragma unroll
            for (int d = 0; d < 18; ++d) s = fma(xr64[d], xm64[d], s);
            sv[s4] = s; smi[s4] = m;
        }

        double cv = -3.0; int cm = 0;
#pragma unroll
        for (int e = 0; e < KSEL; ++e) {
            double lv = sv[0]; int lm = smi[0];
#pragma unroll
            for (int s4 = 1; s4 < 4; ++s4) {
                bool t = (sv[s4] > lv) || (sv[s4] == lv && smi[s4] < lm);
                lv = t ? sv[s4] : lv; lm = t ? smi[s4] : lm;
            }
#pragma unroll
            for (int off = 1; off < 64; off <<= 1) {
                double ov = __shfl_xor(lv, off);
                int    om = __shfl_xor(lm, off);
                bool t = (ov > lv) || (ov == lv && om < lm);
                lv = t ? ov : lv; lm = t ? om : lm;
            }
            if (lane == e) { cv = lv; cm = lm; }
#pragma unroll
            for (int s4 = 0; s4 < 4; ++s4) if (smi[s4] == lm) sv[s4] = -3.0;
        }

        float alpha = ea[0], beta = eb[0];
        float sg = 1.f / (1.f + expf(-(beta + alpha * (float)cv)));
        float v = (lane < KSEL) ? sg : -1e30f;
        float mx = v, of;
        for (int off = 1; off < 64; off <<= 1) { of = __shfl_xor(mx, off); mx = fmaxf(mx, of); }
        float ex = expf(v - mx);
        float sm = ex;
        for (int off = 1; off < 64; off <<= 1) { of = __shfl_xor(sm, off); sm += of; }
        float w = ex / sm;
        if (lane < 16) {
            topi[row * 16 + lane] = (lane < KSEL) ? cm : 0;
            wkout[row * 16 + lane] = (lane < KSEL) ? w : 0.f;
        }
    }
}

// ---------------- K3: weighted gather-aggregate ----------------
__global__ __launch_bounds__(256) void k3_aggregate(
    const float* __restrict__ x, const int* __restrict__ topi, const float* __restrict__ wk,
    float* __restrict__ out)
{
    __shared__ float tile[NN * ROWSTRIDE];   // [pos][20], 16 channels used
    const int tid = threadIdx.x;
    const int pb = blockIdx.x >> 3, cg = blockIdx.x & 7, c0 = cg * 16;
    const int b = pb / 49, g = pb % 49;
    const int gI = g / 7, gJ = g % 7;
    const float* xb = x + ((size_t)b * CIN + c0) * PLANE + (size_t)(gI * 16 * HH + gJ * 16);

#pragma unroll
    for (int rep = 0; rep < 4; ++rep) {
        int linear = rep * 256 + tid;
        int cc = linear >> 6, chunk = linear & 63;
        int pos = chunk * 4, ii = pos >> 4, jj = pos & 15;
        float4 v = *(const float4*)(xb + (size_t)cc * PLANE + ii * HH + jj);
        tile[(pos + 0) * ROWSTRIDE + cc] = v.x;
        tile[(pos + 1) * ROWSTRIDE + cc] = v.y;
        tile[(pos + 2) * ROWSTRIDE + cc] = v.z;
        tile[(pos + 3) * ROWSTRIDE + cc] = v.w;
    }
    __syncthreads();

    const int n = tid;
    const int row = pb * NN + n;
    float acc[16];
#pragma unroll
    for (int c = 0; c < 16; ++c) acc[c] = 0.f;

#pragma unroll
    for (int kq = 0; kq < 4; ++kq) {
        int4   mi4 = ((const int4*)(topi + (size_t)row * 16))[kq];
        float4 w4  = ((const float4*)(wk  + (size_t)row * 16))[kq];
        const int   mis[4] = { mi4.x, mi4.y, mi4.z, mi4.w };
        const float ws4[4] = { w4.x, w4.y, w4.z, w4.w };
#pragma unroll
        for (int u = 0; u < 4; ++u) {
            float w = ws4[u];
            const float4* sp = (const float4*)&tile[mis[u] * ROWSTRIDE];
#pragma unroll
            for (int q = 0; q < 4; ++q) {
                float4 f = sp[q];
                acc[q * 4 + 0] = fmaf(w, f.x, acc[q * 4 + 0]);
                acc[q * 4 + 1] = fmaf(w, f.y, acc[q * 4 + 1]);
                acc[q * 4 + 2] = fmaf(w, f.z, acc[q * 4 + 2]);
                acc[q * 4 + 3] = fmaf(w, f.w, acc[q * 4 + 3]);
            }
        }
    }
    const int ii = n >> 4, jj = n & 15;
    float* ob = out + ((size_t)b * CIN + c0) * PLANE + (size_t)(gI * 16 * HH + gJ * 16) + ii * HH + jj;
#pragma unroll
    for (int cc = 0; cc < 16; ++cc) ob[(size_t)cc * PLANE] = acc[cc];
}

extern "C" void kernel_launch(void* const* d_in, const int* in_sizes, int n_in,
                              void* d_out, int out_size, void* d_ws, size_t ws_size,
                              hipStream_t stream) {
    const float* x  = (const float*)d_in[0];
    const float* fw = (const float*)d_in[1];
    const float* fb = (const float*)d_in[2];
    const float* ea = (const float*)d_in[3];
    const float* eb = (const float*)d_in[4];
    float* out = (float*)d_out;

    int nB = in_sizes[0] / (CIN * PLANE);   // 4
    int nP = nB * 49;                       // 196
    size_t nRows = (size_t)nP * NN;         // 50176

    char* wsb = (char*)d_ws;
    size_t off = 0;
    auto carve = [&](size_t bytes) { char* r = wsb + off; off = (off + bytes + 255) & ~(size_t)255; return r; };
    double*   xa64   = (double*)  carve(nRows * ROWSTRIDE * sizeof(double));
    float*    xa32   = (float*)   carve(nRows * ROWSTRIDE * sizeof(float));
    float*    xa32T  = (float*)   carve((size_t)nP * 18 * NN * sizeof(float));
    int*      topi   = (int*)     carve(nRows * 16 * sizeof(int));
    float*    wk     = (float*)   carve(nRows * 16 * sizeof(float));
    unsigned* dcnt   = (unsigned*)carve(256);
    int*      dlist  = (int*)     carve(nRows * sizeof(int));

    hipLaunchKernelGGL(k1_features, dim3(nP * 4), dim3(256), 0, stream, x, fw, fb, xa64, xa32, xa32T, dcnt);
    hipLaunchKernelGGL(k2_select,   dim3(nP * 16), dim3(256), 0, stream, xa32, xa32T, ea, eb, topi, wk, dcnt, dlist);
    hipLaunchKernelGGL(k2b_dirty,   dim3(256), dim3(64), 0, stream, xa64, ea, eb, dcnt, dlist, topi, wk);
    hipLaunchKernelGGL(k3_aggregate, dim3(nP * 8), dim3(256), 0, stream, x, topi, wk, out);
}

// Round 9
// 150.907 us; speedup vs baseline: 1.3906x; 1.0198x over previous
//
#include <hip/hip_runtime.h>
#include <math.h>

#define KSEL 15
#define CIN 128
#define CF 16
#define HH 112
#define PLANE 12544      // 112*112
#define NN 256
#define ROWSTRIDE 20     // padded row-major feature row (18 used)
#define KVROW 260        // kv row stride in uints (reads lane-consecutive; 1040B rows, 16B-aligned)

static __device__ __forceinline__ unsigned mono32(float f) {
    unsigned u = __float_as_uint(f);
    return ((int)u < 0) ? ~u : (u | 0x80000000u);
}
static __device__ __forceinline__ float demono32(unsigned u) {
    return ((int)u < 0) ? __uint_as_float(u & 0x7FFFFFFFu) : __uint_as_float(~u);
}

// ---------------- K1: features (LDS-staged x, fp64 conv -> augment -> normalize) ----------------
__global__ __launch_bounds__(256) void k1_features(
    const float* __restrict__ x, const float* __restrict__ fw, const float* __restrict__ fb,
    double* __restrict__ xa64, float* __restrict__ xa32T,
    unsigned* __restrict__ dirtyCount)
{
    __shared__ float lfw[CIN * CF];   // 8 KB, [c][d]
    __shared__ float lfb[CF];
    __shared__ float xbuf[32 * 64];   // 8 KB, [cc][px] one 32-channel chunk of this block's 64 pixels
    const int tid = threadIdx.x;
    if (blockIdx.x == 0 && tid == 0) *dirtyCount = 0u;
    const int p  = blockIdx.x >> 2;
    const int n0 = (blockIdx.x & 3) * 64;   // 4 i-rows of 16
    const int b = p / 49, g = p % 49;
    const int gI = g / 7, gJ = g % 7;
    const float* xb = x + (size_t)b * CIN * PLANE + (size_t)(gI * 16 * HH + gJ * 16);
    const int i0 = n0 >> 4;                 // first i-row of this block

    for (int q = tid; q < CIN * CF; q += 256) { int d = q >> 7, c = q & 127; lfw[c * CF + d] = fw[q]; }
    if (tid < CF) lfb[tid] = fb[tid];

    const int nl = tid >> 2, dq = tid & 3;
    const int n = n0 + nl, i = n >> 4, j = n & 15;

    // two accumulator sets (even/odd c) — FMA order identical to previous round (bit-exact)
    double e0 = 0.0, e1 = 0.0, e2 = 0.0, e3 = 0.0;
    double o0 = 0.0, o1 = 0.0, o2 = 0.0, o3 = 0.0;

    for (int c0 = 0; c0 < CIN; c0 += 32) {
        __syncthreads();   // prev chunk consumed (and lfw ready on first iter)
        // cooperative stage: 32 c-planes x 64 px = 512 float4; 2 per thread, 64B segments
#pragma unroll
        for (int rep = 0; rep < 2; ++rep) {
            int idx = rep * 256 + tid;
            int cc = idx >> 4, f4 = idx & 15;
            int li = f4 >> 2, j0 = (f4 & 3) * 4;
            float4 v = *(const float4*)(xb + (size_t)(c0 + cc) * PLANE + (i0 + li) * HH + j0);
            *(float4*)&xbuf[cc * 64 + li * 16 + j0] = v;
        }
        __syncthreads();

#pragma unroll 2
        for (int cc = 0; cc < 32; cc += 2) {
            double xc0 = (double)xbuf[(cc + 0) * 64 + nl];
            double xc1 = (double)xbuf[(cc + 1) * 64 + nl];
            float4 wv0 = *(const float4*)&lfw[(c0 + cc) * CF + dq * 4];
            float4 wv1 = *(const float4*)&lfw[(c0 + cc + 1) * CF + dq * 4];
            e0 = fma(xc0, (double)wv0.x, e0);
            e1 = fma(xc0, (double)wv0.y, e1);
            e2 = fma(xc0, (double)wv0.z, e2);
            e3 = fma(xc0, (double)wv0.w, e3);
            o0 = fma(xc1, (double)wv1.x, o0);
            o1 = fma(xc1, (double)wv1.y, o1);
            o2 = fma(xc1, (double)wv1.z, o2);
            o3 = fma(xc1, (double)wv1.w, o3);
        }
    }
    double a0 = e0 + o0 + (double)lfb[dq * 4 + 0];
    double a1 = e1 + o1 + (double)lfb[dq * 4 + 1];
    double a2 = e2 + o2 + (double)lfb[dq * 4 + 2];
    double a3 = e3 + o3 + (double)lfb[dq * 4 + 3];

    const double GDIV = 4.618802153517006 + 1e-5;
    double gx = ((double)i - 7.5) / GDIV;
    double gy = ((double)j - 7.5) / GDIV;

    double ss = a0 * a0;
    ss = fma(a1, a1, ss); ss = fma(a2, a2, ss); ss = fma(a3, a3, ss);
    if (dq == 3) { ss = fma(gx, gx, ss); ss = fma(gy, gy, ss); }
    ss += __shfl_xor(ss, 1);
    ss += __shfl_xor(ss, 2);
    double nrm = fmax(sqrt(ss), 1e-8);

    size_t ro = ((size_t)p * NN + n) * ROWSTRIDE;
    double f0 = a0 / nrm, f1 = a1 / nrm, f2 = a2 / nrm, f3 = a3 / nrm;
    xa64[ro + dq * 4 + 0] = f0; xa64[ro + dq * 4 + 1] = f1;
    xa64[ro + dq * 4 + 2] = f2; xa64[ro + dq * 4 + 3] = f3;
    // transposed copy for K2's conflict-free B-side reads
    size_t tb = ((size_t)p * 18 + dq * 4) * NN + n;
    xa32T[tb + 0 * NN] = (float)f0;
    xa32T[tb + 1 * NN] = (float)f1;
    xa32T[tb + 2 * NN] = (float)f2;
    xa32T[tb + 3 * NN] = (float)f3;
    if (dq == 3) {
        double g0 = gx / nrm, g1 = gy / nrm;
        xa64[ro + 16] = g0; xa64[ro + 17] = g1; xa64[ro + 18] = 0.0; xa64[ro + 19] = 0.0;
        size_t tg = ((size_t)p * 18 + 16) * NN + n;
        xa32T[tg] = (float)g0; xa32T[tg + NN] = (float)g1;
    }
}

// ---------------- K2: sims -> (kv aliased into tileT) -> sort16+merge ----------------
// LDS 19.8 KB -> 8 blocks/CU; launch_bounds(256,8) targets <=64 VGPR -> 32 waves/CU.
__global__ __launch_bounds__(256, 8) void k2_select(
    const float* __restrict__ xa32T,
    const float* __restrict__ ea, const float* __restrict__ eb,
    int* __restrict__ topi, float* __restrict__ wkout,
    unsigned* __restrict__ dirtyCount, int* __restrict__ dirtyList)
{
    __shared__ float tileT[18 * NN];          // 18 KB, [d][m]; REUSED as kv after phase 1
    __shared__ float rowTile[16 * ROWSTRIDE]; // 1.3 KB, block's 16 rows, row-major
    unsigned* kv = (unsigned*)tileT;          // kv[16][KVROW], 16.6 KB <= 18 KB
    const int tid = threadIdx.x;
    const int p = blockIdx.x >> 4, sub = blockIdx.x & 15;

    // stage transposed tile (coalesced global, consecutive-lane LDS writes: conflict-free)
    const float4* srcT = (const float4*)(xa32T + (size_t)p * 18 * NN);
    for (int q = tid; q < (18 * NN / 4); q += 256)
        ((float4*)tileT)[q] = srcT[q];
    __syncthreads();
    // build this block's 16-row row-major tile from tileT (LDS->LDS, 288 elems)
    {
        int d = tid >> 4, r = tid & 15;
        if (d < 16) rowTile[r * ROWSTRIDE + d] = tileT[d * NN + sub * 16 + r];
        if (tid < 32) {
            int d2 = 16 + (tid >> 4), r2 = tid & 15;
            rowTile[r2 * ROWSTRIDE + d2] = tileT[d2 * NN + sub * 16 + r2];
        }
    }
    __syncthreads();

    // ---- phase 1: sims; wave owns 4 rows, two passes of 2 rows; keys stay in registers ----
    const int w    = tid >> 6;         // wave 0..3
    const int lane = tid & 63;
    const int m0   = lane * 4;

    unsigned keys[16];                 // [half*8 + rowpair*4 + j]
#pragma unroll
    for (int half = 0; half < 2; ++half) {
        const int r0 = w * 4 + half * 2;
        float xr0[18], xr1[18];
        {
            const float* rpA = &rowTile[(r0 + 0) * ROWSTRIDE];
            const float* rpB = &rowTile[(r0 + 1) * ROWSTRIDE];
            float4 t0, t1, t2, t3; float2 tt;
            t0 = *(const float4*)&rpA[0];  t1 = *(const float4*)&rpA[4];
            t2 = *(const float4*)&rpA[8];  t3 = *(const float4*)&rpA[12];
            tt = *(const float2*)&rpA[16];
            xr0[0]=t0.x; xr0[1]=t0.y; xr0[2]=t0.z; xr0[3]=t0.w;
            xr0[4]=t1.x; xr0[5]=t1.y; xr0[6]=t1.z; xr0[7]=t1.w;
            xr0[8]=t2.x; xr0[9]=t2.y; xr0[10]=t2.z; xr0[11]=t2.w;
            xr0[12]=t3.x; xr0[13]=t3.y; xr0[14]=t3.z; xr0[15]=t3.w;
            xr0[16]=tt.x; xr0[17]=tt.y;
            t0 = *(const float4*)&rpB[0];  t1 = *(const float4*)&rpB[4];
            t2 = *(const float4*)&rpB[8];  t3 = *(const float4*)&rpB[12];
            tt = *(const float2*)&rpB[16];
            xr1[0]=t0.x; xr1[1]=t0.y; xr1[2]=t0.z; xr1[3]=t0.w;
            xr1[4]=t1.x; xr1[5]=t1.y; xr1[6]=t1.z; xr1[7]=t1.w;
            xr1[8]=t2.x; xr1[9]=t2.y; xr1[10]=t2.z; xr1[11]=t2.w;
            xr1[12]=t3.x; xr1[13]=t3.y; xr1[14]=t3.z; xr1[15]=t3.w;
            xr1[16]=tt.x; xr1[17]=tt.y;
        }

        float a0 = 0.f, a1 = 0.f, a2 = 0.f, a3 = 0.f;   // row r0
        float b0 = 0.f, b1 = 0.f, b2 = 0.f, b3 = 0.f;   // row r0+1
#pragma unroll
        for (int d = 0; d < 18; ++d) {
            float4 bd = *(const float4*)&tileT[d * NN + m0];   // consecutive lanes: conflict-free
            float xA = xr0[d], xB = xr1[d];
            a0 = fmaf(xA, bd.x, a0); a1 = fmaf(xA, bd.y, a1);
            a2 = fmaf(xA, bd.z, a2); a3 = fmaf(xA, bd.w, a3);
            b0 = fmaf(xB, bd.x, b0); b1 = fmaf(xB, bd.y, b1);
            b2 = fmaf(xB, bd.z, b2); b3 = fmaf(xB, bd.w, b3);
        }
        keys[half * 8 + 0] = (mono32(a0) & 0xFFFFFF00u) | (unsigned)(255 - (m0 + 0));
        keys[half * 8 + 1] = (mono32(a1) & 0xFFFFFF00u) | (unsigned)(255 - (m0 + 1));
        keys[half * 8 + 2] = (mono32(a2) & 0xFFFFFF00u) | (unsigned)(255 - (m0 + 2));
        keys[half * 8 + 3] = (mono32(a3) & 0xFFFFFF00u) | (unsigned)(255 - (m0 + 3));
        keys[half * 8 + 4] = (mono32(b0) & 0xFFFFFF00u) | (unsigned)(255 - (m0 + 0));
        keys[half * 8 + 5] = (mono32(b1) & 0xFFFFFF00u) | (unsigned)(255 - (m0 + 1));
        keys[half * 8 + 6] = (mono32(b2) & 0xFFFFFF00u) | (unsigned)(255 - (m0 + 2));
        keys[half * 8 + 7] = (mono32(b3) & 0xFFFFFF00u) | (unsigned)(255 - (m0 + 3));
    }
    __syncthreads();   // ALL waves' tileT reads complete before kv overwrites it

#pragma unroll
    for (int half = 0; half < 2; ++half) {
        const int r0 = w * 4 + half * 2;
        *(uint4*)&kv[(r0 + 0) * KVROW + m0] =
            make_uint4(keys[half*8+0], keys[half*8+1], keys[half*8+2], keys[half*8+3]);
        *(uint4*)&kv[(r0 + 1) * KVROW + m0] =
            make_uint4(keys[half*8+4], keys[half*8+5], keys[half*8+6], keys[half*8+7]);
    }
    __syncthreads();

    // ---- phase 2: per-row top-16 (16 lanes/row; lane owns m ≡ l16 mod 16) ----
    const int l16 = tid & 15;
    const int rb  = tid >> 4;
    const int row = p * NN + sub * 16 + rb;
    const int kvb = rb * KVROW + l16;

    unsigned k[16];
#pragma unroll
    for (int s = 0; s < 16; ++s) k[s] = kv[kvb + 16 * s];   // b32, lanes consecutive: free

    // bitonic sort ascending (registers)
#pragma unroll
    for (int kk = 2; kk <= 16; kk <<= 1) {
#pragma unroll
        for (int jj = kk >> 1; jj > 0; jj >>= 1) {
#pragma unroll
            for (int ii = 0; ii < 16; ++ii) {
                int ll = ii ^ jj;
                if (ll > ii) {
                    bool up = ((ii & kk) == 0);
                    unsigned a = k[ii], bv = k[ll];
                    bool sw = up ? (a > bv) : (a < bv);
                    k[ii] = sw ? bv : a; k[ll] = sw ? a : bv;
                }
            }
        }
    }
    // write back sorted list (same-thread slots; only read by this thread's rare fallback)
#pragma unroll
    for (int s = 0; s < 16; ++s) kv[kvb + 16 * s] = k[s];

    // 16-round head merge; next-head from a 4-deep register window, LDS fallback (rare)
    unsigned h14 = k[14], h13 = k[13], h12 = k[12], h11 = k[11];
    int ptr = 15;
    unsigned myhead = k[15];
    unsigned mycand = 0;
#pragma unroll
    for (int e = 0; e < 16; ++e) {
        unsigned W = myhead, o;
        o = __shfl_xor(W, 1);  W = (o > W) ? o : W;
        o = __shfl_xor(W, 2);  W = (o > W) ? o : W;
        o = __shfl_xor(W, 4);  W = (o > W) ? o : W;
        o = __shfl_xor(W, 8);  W = (o > W) ? o : W;
        if (l16 == e) mycand = W;
        bool won = (myhead == W);
        if (won) {
            ptr--;
            int rp = ptr < 0 ? 0 : ptr;
            unsigned nh = h14;
            nh = (rp == 13) ? h13 : nh;
            nh = (rp == 12) ? h12 : nh;
            nh = (rp == 11) ? h11 : nh;
            if (rp <= 10) nh = kv[kvb + 16 * rp];   // divergent, rare
            myhead = nh;
        }
    }

    // certification: fp64 top-15 set == fp32 top-15 set unless boundary gap too small
    unsigned v15 = __shfl(mycand, 14, 16);
    unsigned v16 = __shfl(mycand, 15, 16);
    float lo = demono32(v15 & 0xFFFFFF00u) - 1e-5f;
    float hi = demono32((v16 & 0xFFFFFF00u) + 0x100u) + 1e-5f;
    bool dirty = !(hi < lo);
    if (l16 == 0 && dirty) {
        unsigned slot = atomicAdd(dirtyCount, 1u);
        dirtyList[slot] = row;
    }

    // weights from fp32 sims (clean rows; dirty rows overwritten by K2b)
    int mym = 255 - (int)(mycand & 0xFFu);
    float sv = demono32(mycand & 0xFFFFFF00u);
    float alpha = ea[0], beta = eb[0];
    float sg = 1.f / (1.f + expf(-(beta + alpha * sv)));
    float v = (l16 < KSEL) ? sg : -1e30f;
    float mx = v, of;
    of = __shfl_xor(mx, 1); mx = fmaxf(mx, of);
    of = __shfl_xor(mx, 2); mx = fmaxf(mx, of);
    of = __shfl_xor(mx, 4); mx = fmaxf(mx, of);
    of = __shfl_xor(mx, 8); mx = fmaxf(mx, of);
    float ex = expf(v - mx);
    float sm = ex;
    of = __shfl_xor(sm, 1); sm += of;
    of = __shfl_xor(sm, 2); sm += of;
    of = __shfl_xor(sm, 4); sm += of;
    of = __shfl_xor(sm, 8); sm += of;

    topi[row * 16 + l16] = mym;
    wkout[row * 16 + l16] = (l16 < KSEL) ? (ex / sm) : 0.f;
}

// ---------------- K2b: exact fp64 redo for dirty rows (persistent, wave per row) ----------------
__global__ __launch_bounds__(64) void k2b_dirty(
    const double* __restrict__ xa64, const float* __restrict__ ea, const float* __restrict__ eb,
    const unsigned* __restrict__ dirtyCount, const int* __restrict__ dirtyList,
    int* __restrict__ topi, float* __restrict__ wkout)
{
    const int nd = (int)*dirtyCount;
    const int lane = threadIdx.x;
    for (int idx = blockIdx.x; idx < nd; idx += gridDim.x) {
        const int row = dirtyList[idx];
        const int p = row >> 8;
        const double* xr64 = xa64 + (size_t)row * ROWSTRIDE;

        double sv[4]; int smi[4];
#pragma unroll
        for (int s4 = 0; s4 < 4; ++s4) {
            int m = s4 * 64 + lane;
            const double* xm64 = xa64 + ((size_t)p * NN + m) * ROWSTRIDE;
            double s = 0.0;
#pragma unroll
            for (int d = 0; d < 18; ++d) s = fma(xr64[d], xm64[d], s);
            sv[s4] = s; smi[s4] = m;
        }

        double cv = -3.0; int cm = 0;
#pragma unroll
        for (int e = 0; e < KSEL; ++e) {
            double lv = sv[0]; int lm = smi[0];
#pragma unroll
            for (int s4 = 1; s4 < 4; ++s4) {
                bool t = (sv[s4] > lv) || (sv[s4] == lv && smi[s4] < lm);
                lv = t ? sv[s4] : lv; lm = t ? smi[s4] : lm;
            }
#pragma unroll
            for (int off = 1; off < 64; off <<= 1) {
                double ov = __shfl_xor(lv, off);
                int    om = __shfl_xor(lm, off);
                bool t = (ov > lv) || (ov == lv && om < lm);
                lv = t ? ov : lv; lm = t ? om : lm;
            }
            if (lane == e) { cv = lv; cm = lm; }
#pragma unroll
            for (int s4 = 0; s4 < 4; ++s4) if (smi[s4] == lm) sv[s4] = -3.0;
        }

        float alpha = ea[0], beta = eb[0];
        float sg = 1.f / (1.f + expf(-(beta + alpha * (float)cv)));
        float v = (lane < KSEL) ? sg : -1e30f;
        float mx = v, of;
        for (int off = 1; off < 64; off <<= 1) { of = __shfl_xor(mx, off); mx = fmaxf(mx, of); }
        float ex = expf(v - mx);
        float sm = ex;
        for (int off = 1; off < 64; off <<= 1) { of = __shfl_xor(sm, off); sm += of; }
        float w = ex / sm;
        if (lane < 16) {
            topi[row * 16 + lane] = (lane < KSEL) ? cm : 0;
            wkout[row * 16 + lane] = (lane < KSEL) ? w : 0.f;
        }
    }
}

// ---------------- K3: weighted gather-aggregate ----------------
__global__ __launch_bounds__(256) void k3_aggregate(
    const float* __restrict__ x, const int* __restrict__ topi, const float* __restrict__ wk,
    float* __restrict__ out)
{
    __shared__ float tile[NN * ROWSTRIDE];   // [pos][20], 16 channels used
    const int tid = threadIdx.x;
    const int pb = blockIdx.x >> 3, cg = blockIdx.x & 7, c0 = cg * 16;
    const int b = pb / 49, g = pb % 49;
    const int gI = g / 7, gJ = g % 7;
    const float* xb = x + ((size_t)b * CIN + c0) * PLANE + (size_t)(gI * 16 * HH + gJ * 16);

#pragma unroll
    for (int rep = 0; rep < 4; ++rep) {
        int linear = rep * 256 + tid;
        int cc = linear >> 6, chunk = linear & 63;
        int pos = chunk * 4, ii = pos >> 4, jj = pos & 15;
        float4 v = *(const float4*)(xb + (size_t)cc * PLANE + ii * HH + jj);
        tile[(pos + 0) * ROWSTRIDE + cc] = v.x;
        tile[(pos + 1) * ROWSTRIDE + cc] = v.y;
        tile[(pos + 2) * ROWSTRIDE + cc] = v.z;
        tile[(pos + 3) * ROWSTRIDE + cc] = v.w;
    }
    __syncthreads();

    const int n = tid;
    const int row = pb * NN + n;
    float acc[16];
#pragma unroll
    for (int c = 0; c < 16; ++c) acc[c] = 0.f;

#pragma unroll
    for (int kq = 0; kq < 4; ++kq) {
        int4   mi4 = ((const int4*)(topi + (size_t)row * 16))[kq];
        float4 w4  = ((const float4*)(wk  + (size_t)row * 16))[kq];
        const int   mis[4] = { mi4.x, mi4.y, mi4.z, mi4.w };
        const float ws4[4] = { w4.x, w4.y, w4.z, w4.w };
#pragma unroll
        for (int u = 0; u < 4; ++u) {
            float w = ws4[u];
            const float4* sp = (const float4*)&tile[mis[u] * ROWSTRIDE];
#pragma unroll
            for (int q = 0; q < 4; ++q) {
                float4 f = sp[q];
                acc[q * 4 + 0] = fmaf(w, f.x, acc[q * 4 + 0]);
                acc[q * 4 + 1] = fmaf(w, f.y, acc[q * 4 + 1]);
                acc[q * 4 + 2] = fmaf(w, f.z, acc[q * 4 + 2]);
                acc[q * 4 + 3] = fmaf(w, f.w, acc[q * 4 + 3]);
            }
        }
    }
    const int ii = n >> 4, jj = n & 15;
    float* ob = out + ((size_t)b * CIN + c0) * PLANE + (size_t)(gI * 16 * HH + gJ * 16) + ii * HH + jj;
#pragma unroll
    for (int cc = 0; cc < 16; ++cc) ob[(size_t)cc * PLANE] = acc[cc];
}

extern "C" void kernel_launch(void* const* d_in, const int* in_sizes, int n_in,
                              void* d_out, int out_size, void* d_ws, size_t ws_size,
                              hipStream_t stream) {
    const float* x  = (const float*)d_in[0];
    const float* fw = (const float*)d_in[1];
    const float* fb = (const float*)d_in[2];
    const float* ea = (const float*)d_in[3];
    const float* eb = (const float*)d_in[4];
    float* out = (float*)d_out;

    int nB = in_sizes[0] / (CIN * PLANE);   // 4
    int nP = nB * 49;                       // 196
    size_t nRows = (size_t)nP * NN;         // 50176

    char* wsb = (char*)d_ws;
    size_t off = 0;
    auto carve = [&](size_t bytes) { char* r = wsb + off; off = (off + bytes + 255) & ~(size_t)255; return r; };
    double*   xa64   = (double*)  carve(nRows * ROWSTRIDE * sizeof(double));
    float*    xa32T  = (float*)   carve((size_t)nP * 18 * NN * sizeof(float));
    int*      topi   = (int*)     carve(nRows * 16 * sizeof(int));
    float*    wk     = (float*)   carve(nRows * 16 * sizeof(float));
    unsigned* dcnt   = (unsigned*)carve(256);
    int*      dlist  = (int*)     carve(nRows * sizeof(int));

    hipLaunchKernelGGL(k1_features, dim3(nP * 4), dim3(256), 0, stream, x, fw, fb, xa64, xa32T, dcnt);
    hipLaunchKernelGGL(k2_select,   dim3(nP * 16), dim3(256), 0, stream, xa32T, ea, eb, topi, wk, dcnt, dlist);
    hipLaunchKernelGGL(k2b_dirty,   dim3(256), dim3(64), 0, stream, xa64, ea, eb, dcnt, dlist, topi, wk);
    hipLaunchKernelGGL(k3_aggregate, dim3(nP * 8), dim3(256), 0, stream, x, topi, wk, out);
}